// Round 3
// baseline (198.480 us; speedup 1.0000x reference)
//
#include <hip/hip_runtime.h>
#include <hip/hip_bf16.h>

#define EPSBN 1e-5f

typedef short short8 __attribute__((ext_vector_type(8)));
typedef float f32x16 __attribute__((ext_vector_type(16)));

static __device__ __forceinline__ unsigned short f2u(float f){
  __hip_bfloat16 h = __float2bfloat16(f);
  union { __hip_bfloat16 h; unsigned short u; } c; c.h = h; return c.u;
}

// ---- workspace layout (bytes) ----
#define WS_G     2048
#define WS_S     7168
#define WS_T     8192
#define WS_AGGB  16384      // 147456 bf16  [b][cc2][s9][o32][ci32]
#define WS_XSRC  327680     // 33554432 B fp32 [b][g16][i128][j128][4ci]

// ------- K1: transpose fp32 x -> [b][ci4-group][i][j][4ci] (16B granules), GAP fused -------
// grid: 1024 = b(8) x g(16) x strip(8 of 16 rows); LDS 32.5KB -> 4 blocks/CU.
__global__ __launch_bounds__(256) void k_tr(const float* __restrict__ x,
                                            float* __restrict__ xsrc,
                                            float* __restrict__ g)
{
  __shared__ float xl[4*16*128];   // 32768 B [ci4][r16][c128]
  __shared__ float w[128];
  int tid = threadIdx.x;
  int bi  = blockIdx.x;
  int strip = bi & 7, gq = (bi >> 3) & 15, b = bi >> 7;
  int r0 = strip * 16;

  if (tid < 128){
    int i = tid;
    float s = 0.f;
    int rstart = max(0, (int)floorf((float)(i-1)*(255.0f/127.0f)));
    #pragma unroll
    for (int k = 0; k < 8; ++k){
      int r = rstart + k;
      if (r <= 255){
        float pos = (float)r * (127.0f/255.0f);
        int i0 = (int)pos; float fr = pos - (float)i0; int i1 = min(i0+1,127);
        if (i0 == i) s += 1.0f - fr;
        if (i1 == i) s += fr;
      }
    }
    w[i] = s;
  }
  // load 4 ci planes x 16 rows x 128 cols (float4, coalesced)
  #pragma unroll
  for (int k = 0; k < 8; ++k){
    int n = tid + (k << 8);
    int ci = n >> 9, r = (n >> 5) & 15, c4 = n & 31;
    *(float4*)&xl[(ci*16 + r)*128 + c4*4] =
      *(const float4*)&x[(((size_t)(b*64 + gq*4 + ci)) << 14) + (r0 + r)*128 + c4*4];
  }
  __syncthreads();

  // transpose-store (float4 of 4 ci per position) + fused GAP partials
  float g0=0.f, g1=0.f, g2=0.f, g3=0.f;
  #pragma unroll
  for (int k = 0; k < 8; ++k){
    int m = tid + (k << 8);
    int r = m >> 7, c = m & 127;
    float v0 = xl[(0*16 + r)*128 + c];
    float v1 = xl[(1*16 + r)*128 + c];
    float v2 = xl[(2*16 + r)*128 + c];
    float v3 = xl[(3*16 + r)*128 + c];
    float wt = w[r0 + r] * w[c];
    g0 += wt*v0; g1 += wt*v1; g2 += wt*v2; g3 += wt*v3;
    float4 o; o.x = v0; o.y = v1; o.z = v2; o.w = v3;
    *(float4*)&xsrc[(((((size_t)(b*16 + gq)) << 14) + (size_t)((r0 + r)*128 + c)) << 2)] = o;
  }
  #pragma unroll
  for (int off = 32; off; off >>= 1){
    g0 += __shfl_down(g0, off);
    g1 += __shfl_down(g1, off);
    g2 += __shfl_down(g2, off);
    g3 += __shfl_down(g3, off);
  }
  if ((tid & 63) == 0){
    const float inv = 1.0f/65536.0f;
    atomicAdd(&g[b*64 + gq*4 + 0], g0*inv);
    atomicAdd(&g[b*64 + gq*4 + 1], g1*inv);
    atomicAdd(&g[b*64 + gq*4 + 2], g2*inv);
    atomicAdd(&g[b*64 + gq*4 + 3], g3*inv);
  }
}

// ------- K2: attention MLP (redundant per block) + aggregated bf16 filters -------
// layout out: [b][cc2][s9][o32][ci32]
__global__ __launch_bounds__(256) void k_aggw(const float* __restrict__ g,
                      const float* __restrict__ fc_w,
                      const float* __restrict__ bga, const float* __restrict__ bba,
                      const float* __restrict__ bma, const float* __restrict__ bva,
                      const float* __restrict__ ch_w, const float* __restrict__ ch_b,
                      const float* __restrict__ fil_w, const float* __restrict__ fil_b,
                      const float* __restrict__ sp_w, const float* __restrict__ sp_b,
                      const float* __restrict__ k_w, const float* __restrict__ k_b,
                      const float* __restrict__ bn_g, const float* __restrict__ bn_b,
                      const float* __restrict__ bn_m, const float* __restrict__ bn_v,
                      const float* __restrict__ weight,
                      unsigned short* __restrict__ aggb,
                      float* __restrict__ sS, float* __restrict__ tT)
{
  __shared__ float h[8][16];
  int tid = threadIdx.x;
  if (tid < 128){
    int b = tid >> 4, a = tid & 15;
    float acc = 0.f;
    for (int c = 0; c < 64; ++c) acc += g[b*64+c] * fc_w[a*64+c];
    float v = (acc - bma[a]) * rsqrtf(bva[a] + EPSBN) * bga[a] + bba[a];
    h[b][a] = fmaxf(v, 0.f);
  }
  __syncthreads();

  int idx = blockIdx.x*256 + tid;      // < 147456
  int ci_l = idx & 31;
  int o    = (idx >> 5) & 31;
  int s    = (idx >> 10) % 9;
  int t2   = (idx >> 10) / 9;          // b*2+cc
  int cc   = t2 & 1, b = t2 >> 1;
  int ci   = cc*32 + ci_l;

  const float* hb = h[b];
  float zc = ch_b[ci], zs = sp_b[s];
  float z0 = k_b[0],  z1 = k_b[1];
  #pragma unroll
  for (int a = 0; a < 16; ++a){
    float hv = hb[a];
    zc += hv*ch_w[ci*16+a];
    zs += hv*sp_w[s*16+a];
    z0 += hv*k_w[a];
    z1 += hv*k_w[16+a];
  }
  float chv = 1.f/(1.f+expf(-zc));
  float spv = 1.f/(1.f+expf(-zs));
  float m = fmaxf(z0,z1);
  float e0 = expf(z0-m), e1 = expf(z1-m), inv = 1.f/(e0+e1);
  float ka0 = e0*inv, ka1 = e1*inv;
  float w0 = weight[(o*64+ci)*9+s];
  float w1 = weight[((32+o)*64+ci)*9+s];
  aggb[idx] = f2u(chv*spv*(ka0*w0 + ka1*w1));

  if (blockIdx.x == 0){
    int bb = tid >> 5, oo = tid & 31;
    float z = fil_b[oo];
    #pragma unroll
    for (int a = 0; a < 16; ++a) z += h[bb][a]*fil_w[oo*16+a];
    float f = 1.f/(1.f+expf(-z));
    float invs = rsqrtf(bn_v[oo] + EPSBN);
    sS[tid] = f * bn_g[oo] * invs;
    if (bb == 0) tT[oo] = bn_b[oo] - bn_m[oo]*bn_g[oo]*invs;
  }
}

// -------- K3: fused upsample + MFMA implicit-GEMM conv + BN + GELU --------
// block: 16x32 output px, all 32 Cout; 4 waves x 4 acc tiles; 2 cc chunks of 32 ci.
// Per cc: stage fp32 source region (11x20 pos x 32 ci) -> in-LDS bilinear interp -> xt (bf16).
// cc=1 source prefetched into registers before the cc=0 K-loop (proven round-1 pattern).
#define XT_STRIDE 40   // 32 ci + 8 pad halfwords (80 B, 16B-aligned, bank-balanced)

static __device__ __forceinline__ float4 lerp4(float4 a, float4 b, float w){
  float4 r;
  r.x = a.x + (b.x - a.x)*w;
  r.y = a.y + (b.y - a.y)*w;
  r.z = a.z + (b.z - a.z)*w;
  r.w = a.w + (b.w - a.w)*w;
  return r;
}

__global__ __launch_bounds__(256) void k_conv(const float* __restrict__ xsrc,
                                              const unsigned short* __restrict__ aggb,
                                              const float* __restrict__ sS,
                                              const float* __restrict__ tT,
                                              float* __restrict__ out)
{
  __shared__ float srcb[1792*4];                   // 28672 B  [i11+pad][j20][c8][4ci]
  __shared__ unsigned short xt[18*34*XT_STRIDE];   // 48960 B
  __shared__ float sSs[32], tTs[32];

  int tid = threadIdx.x;
  int bi  = blockIdx.x;
  int sw  = ((bi & 7) << 7) + (bi >> 3);     // nwg=1024 -> xcd*128 + idx (bijective)
  int b   = sw >> 7, t = sw & 127;
  int p0  = (t >> 3) * 16, q0 = (t & 7) * 32;
  int lane = tid & 63, wv = tid >> 6;
  if (tid < 32){ sSs[tid] = sS[b*32+tid]; tTs[tid] = tT[tid]; }

  const float SF = 127.0f/255.0f;
  int i_lo = (int)((float)max(p0-1,0)*SF);
  int j_lo = (int)((float)max(q0-1,0)*SF);

  f32x16 acc[4];
  #pragma unroll
  for (int i = 0; i < 16; ++i){ acc[0][i]=0.f; acc[1][i]=0.f; acc[2][i]=0.f; acc[3][i]=0.f; }

  int n     = lane & 31;        // Cout row for A, px col for B/C
  int kq    = lane >> 5;        // k-half
  int rhalf = n >> 4;
  int qb    = n & 15;
  int wrow  = wv * 4;           // wave owns px rows wrow..wrow+3

  // ---- stage cc=0 source region (fp32, 16B granules, clamped addresses) ----
  #pragma unroll
  for (int k = 0; k < 7; ++k){
    int e = tid + (k << 8);                  // 1792 granules exactly
    int i = e/160, rem = e - i*160, j = rem >> 3, c = rem & 7;
    int ig = min(i_lo + i, 127), jg = min(j_lo + j, 127);
    *(float4*)&srcb[e << 2] =
      *(const float4*)&xsrc[((((size_t)(b*16 + c)) << 14) + (size_t)(ig*128 + jg)) << 2];
  }
  __syncthreads();

  // ---- in-LDS bilinear interp: srcb -> xt (covers all 18x34 pos x 32 ci) ----
  auto interp = [&](){
    #pragma unroll
    for (int k = 0; k < 10; ++k){
      int m = tid + (k << 8); if (m >= 2448) m -= 2448;   // dupes benign
      int cq = m & 7; int tt = m >> 3; int rr = tt/17; int qp = tt - rr*17;
      int gr = p0 - 1 + rr;
      int xbase = (rr*34 + 2*qp)*XT_STRIDE + cq*4;        // halfword index
      bool rv = ((unsigned)gr < 256u);
      float pos_r = (float)gr * SF;
      int i0 = (int)pos_r; float wh = pos_r - (float)i0;
      int io0 = 0, io1 = 0;
      if (rv){ io0 = i0 - i_lo; io1 = min(i0+1,127) - i_lo; }
      #pragma unroll
      for (int cI = 0; cI < 2; ++cI){
        int gq = q0 - 1 + 2*qp + cI;
        bool cv = rv && ((unsigned)gq < 256u);
        float4 v = {0.f,0.f,0.f,0.f};
        if (cv){
          float pos_c = (float)gq * SF;
          int j0 = (int)pos_c; float ww = pos_c - (float)j0;
          int jo0 = j0 - j_lo, jo1 = min(j0+1,127) - j_lo;
          float4 c00 = *(const float4*)&srcb[(io0*160 + jo0*8 + cq) << 2];
          float4 c01 = *(const float4*)&srcb[(io0*160 + jo1*8 + cq) << 2];
          float4 c10 = *(const float4*)&srcb[(io1*160 + jo0*8 + cq) << 2];
          float4 c11 = *(const float4*)&srcb[(io1*160 + jo1*8 + cq) << 2];
          float4 h0 = lerp4(c00, c01, ww);
          float4 h1 = lerp4(c10, c11, ww);
          v = lerp4(h0, h1, wh);
        }
        unsigned lo = (unsigned)f2u(v.x) | (((unsigned)f2u(v.y)) << 16);
        unsigned hi = (unsigned)f2u(v.z) | (((unsigned)f2u(v.w)) << 16);
        uint2 pk; pk.x = lo; pk.y = hi;
        *(uint2*)&xt[xbase + cI*XT_STRIDE] = pk;
      }
    }
  };
  interp();
  __syncthreads();

  // ---- prefetch cc=1 source into registers (latency hides under cc=0 K-loop) ----
  float4 pre[7];
  #pragma unroll
  for (int k = 0; k < 7; ++k){
    int e = tid + (k << 8);
    int i = e/160, rem = e - i*160, j = rem >> 3, c = rem & 7;
    int ig = min(i_lo + i, 127), jg = min(j_lo + j, 127);
    pre[k] = *(const float4*)&xsrc[((((size_t)(b*16 + 8 + c)) << 14) + (size_t)(ig*128 + jg)) << 2];
  }

  // K-loop over a cc chunk; A-fragments software-pipelined, shared by 4 acc tiles
  auto kloop = [&](const unsigned short* ab){
    short8 a0 = *(const short8*)&ab[0];
    short8 a1 = *(const short8*)&ab[16];
    #pragma unroll
    for (int s = 0; s < 9; ++s){
      int sn = (s < 8) ? s+1 : 8;
      short8 na0 = *(const short8*)&ab[sn*1024];
      short8 na1 = *(const short8*)&ab[sn*1024+16];
      const int ky = s/3, kx = s%3;
      #pragma unroll
      for (int tt = 0; tt < 4; ++tt){
        const int rp = tt >> 1, cb = tt & 1;
        const unsigned short* xrow =
          &xt[((wrow + 2*rp + rhalf + ky)*34 + cb*16 + qb + kx)*XT_STRIDE + kq*8];
        short8 bv0 = *(const short8*)&xrow[0];
        short8 bv1 = *(const short8*)&xrow[16];
        acc[tt] = __builtin_amdgcn_mfma_f32_32x32x16_bf16(a0, bv0, acc[tt], 0, 0, 0);
        acc[tt] = __builtin_amdgcn_mfma_f32_32x32x16_bf16(a1, bv1, acc[tt], 0, 0, 0);
      }
      a0 = na0; a1 = na1;
    }
  };

  kloop(aggb + (size_t)(b*2+0)*9216 + n*32 + kq*8);
  __syncthreads();
  // commit prefetched cc=1 source
  #pragma unroll
  for (int k = 0; k < 7; ++k){
    int e = tid + (k << 8);
    *(float4*)&srcb[e << 2] = pre[k];
  }
  __syncthreads();
  interp();
  __syncthreads();
  kloop(aggb + (size_t)(b*2+1)*9216 + n*32 + kq*8);

  // epilogue: scale/bias + GELU(exact erf), fp32 stores
  #pragma unroll
  for (int tt = 0; tt < 4; ++tt){
    int rp = tt >> 1, cb = tt & 1;
    int p = p0 + wrow + 2*rp + rhalf;
    int q = q0 + cb*16 + qb;
    #pragma unroll
    for (int r = 0; r < 16; ++r){
      int o = (r & 3) + 8*(r >> 2) + 4*kq;
      float valv = acc[tt][r]*sSs[o] + tTs[o];
      float gl  = 0.5f*valv*(1.f + erff(valv*0.70710678118f));
      out[(((size_t)(b*32+o)) << 16) + (p << 8) + q] = gl;
    }
  }
}

extern "C" void kernel_launch(void* const* d_in, const int* in_sizes, int n_in,
                              void* d_out, int out_size, void* d_ws, size_t ws_size,
                              hipStream_t stream)
{
  const float* x     = (const float*)d_in[0];
  const float* fc_w  = (const float*)d_in[1];
  const float* bga   = (const float*)d_in[2];
  const float* bba   = (const float*)d_in[3];
  const float* bma   = (const float*)d_in[4];
  const float* bva   = (const float*)d_in[5];
  const float* ch_w  = (const float*)d_in[6];
  const float* ch_b  = (const float*)d_in[7];
  const float* fil_w = (const float*)d_in[8];
  const float* fil_b = (const float*)d_in[9];
  const float* sp_w  = (const float*)d_in[10];
  const float* sp_b  = (const float*)d_in[11];
  const float* k_w   = (const float*)d_in[12];
  const float* k_b   = (const float*)d_in[13];
  const float* weight= (const float*)d_in[14];
  const float* bn_g  = (const float*)d_in[15];
  const float* bn_b  = (const float*)d_in[16];
  const float* bn_m  = (const float*)d_in[17];
  const float* bn_v  = (const float*)d_in[18];

  char* ws = (char*)d_ws;
  float* g    = (float*)(ws + WS_G);
  float* sS   = (float*)(ws + WS_S);
  float* tT   = (float*)(ws + WS_T);
  unsigned short* aggb = (unsigned short*)(ws + WS_AGGB);
  float* xsrc = (float*)(ws + WS_XSRC);
  float* out  = (float*)d_out;

  hipMemsetAsync(g, 0, 512*sizeof(float), stream);
  hipLaunchKernelGGL(k_tr,   dim3(1024), dim3(256), 0, stream, x, xsrc, g);
  hipLaunchKernelGGL(k_aggw, dim3(576),  dim3(256), 0, stream, g, fc_w, bga, bba, bma, bva,
                     ch_w, ch_b, fil_w, fil_b, sp_w, sp_b, k_w, k_b,
                     bn_g, bn_b, bn_m, bn_v, weight, aggb, sS, tT);
  hipLaunchKernelGGL(k_conv, dim3(1024), dim3(256), 0, stream, xsrc, aggb, sS, tT, out);
}